// Round 1
// baseline (2426.082 us; speedup 1.0000x reference)
//
#include <hip/hip_runtime.h>
#include <cmath>

typedef __attribute__((ext_vector_type(8))) short short8;
typedef __attribute__((ext_vector_type(4))) float floatx4;

__device__ __forceinline__ unsigned short f2bf(float f) {
  union { float f; unsigned u; } c; c.f = f;
  unsigned u = c.u;
  u += 0x7fffu + ((u >> 16) & 1u);
  return (unsigned short)(u >> 16);
}

// ---------------- elementwise cast fp32 -> bf16 (4/thread) ----------------
__global__ void cast_f32_bf16(const float* __restrict__ x, unsigned short* __restrict__ y, int n) {
  int i = (blockIdx.x * 256 + threadIdx.x) * 4;
  if (i >= n) return;
  float4 v = *(const float4*)(x + i);
  ushort4 o;
  o.x = f2bf(v.x); o.y = f2bf(v.y); o.z = f2bf(v.z); o.w = f2bf(v.w);
  *(ushort4*)(y + i) = o;
}

// ------------- centers: cast to bf16 + squared row norms (d=1024) -------------
__global__ void prep_centers(const float* __restrict__ c, unsigned short* __restrict__ cb,
                             float* __restrict__ cn) {
  int row = blockIdx.x, t = threadIdx.x;  // 256 threads, 4 elems each
  const float* cr = c + (size_t)row * 1024;
  float4 v = *(const float4*)(cr + t * 4);
  ushort4 o; o.x = f2bf(v.x); o.y = f2bf(v.y); o.z = f2bf(v.z); o.w = f2bf(v.w);
  *(ushort4*)(cb + (size_t)row * 1024 + t * 4) = o;
  float s = v.x * v.x + v.y * v.y + v.z * v.z + v.w * v.w;
  #pragma unroll
  for (int off = 32; off > 0; off >>= 1) s += __shfl_down(s, off, 64);
  __shared__ float ws[4];
  if ((t & 63) == 0) ws[t >> 6] = s;
  __syncthreads();
  if (t == 0) cn[row] = ws[0] + ws[1] + ws[2] + ws[3];
}

// ------------- column softmax over ST[ncur][nprev] (fp16), E overwrites ST (bf16) -------------
__global__ void softmax_col(_Float16* __restrict__ ST, float* __restrict__ linv,
                            int ncur, int nprev) {
  int i = blockIdx.x * 256 + threadIdx.x;  // nprev % 256 == 0 for all levels
  float m = -1e30f, l = 0.f;
  for (int j = 0; j < ncur; ++j) {
    float x = (float)ST[(size_t)j * nprev + i];
    if (x > m) { l *= __expf(m - x); m = x; }
    l += __expf(x - m);
  }
  linv[i] = 1.0f / l;
  unsigned short* E = (unsigned short*)ST;
  for (int j = 0; j < ncur; ++j) {
    size_t o = (size_t)j * nprev + i;
    float x = (float)ST[o];
    E[o] = f2bf(__expf(x - m));  // in place: same thread reads then writes same elem
  }
}

// ---------------- NT bf16 MFMA GEMM: C[M][N] = A[M][K] * B[N][K]^T ----------------
enum { EP_LOGIT = 0, EP_TANH = 1, EP_BF16 = 2, EP_F32 = 3 };

template<int BM, int BN, int EPI>
__launch_bounds__(256, 2)
__global__ void gemm_nt(const unsigned short* __restrict__ A,
                        const unsigned short* __restrict__ B,
                        void* __restrict__ Cout,
                        const float* __restrict__ aux1,   // cn[M] or bias[M]
                        const float* __restrict__ aux2,   // linv[N]
                        int M, int N, int K) {
  constexpr int BK = 64, PAD = 8, LD = BK + PAD;  // pad keeps 16B alignment, staggers banks
  constexpr int WTM = BM / 2, WTN = BN / 2;
  constexpr int FM = WTM / 16, FN = WTN / 16;
  __shared__ __align__(16) unsigned short As[BM * LD];
  __shared__ __align__(16) unsigned short Bs[BN * LD];
  const int tid  = threadIdx.x;
  const int lane = tid & 63;
  const int wave = tid >> 6;
  const int wm = wave >> 1, wn = wave & 1;
  const int mBase = blockIdx.x * BM, nBase = blockIdx.y * BN;
  const int lr    = lane & 15;           // fragment row (A: m, B: n)
  const int kHalf = (lane >> 4) << 3;    // fragment k offset: 0,8,16,24

  floatx4 acc[FM][FN] = {};
  constexpr int AV = BM * BK / (256 * 8);
  constexpr int BV = BN * BK / (256 * 8);

  for (int k0 = 0; k0 < K; k0 += BK) {   // K % 64 == 0 for all call sites
    #pragma unroll
    for (int v = 0; v < AV; ++v) {
      int idx = v * 256 + tid;
      int r = idx >> 3, cc = (idx & 7) << 3;
      int gm = mBase + r;
      short8 val = {0, 0, 0, 0, 0, 0, 0, 0};
      if (gm < M) val = *(const short8*)(A + (size_t)gm * K + k0 + cc);
      *(short8*)(&As[r * LD + cc]) = val;
    }
    #pragma unroll
    for (int v = 0; v < BV; ++v) {
      int idx = v * 256 + tid;
      int r = idx >> 3, cc = (idx & 7) << 3;
      int gn = nBase + r;
      short8 val = {0, 0, 0, 0, 0, 0, 0, 0};
      if (gn < N) val = *(const short8*)(B + (size_t)gn * K + k0 + cc);
      *(short8*)(&Bs[r * LD + cc]) = val;
    }
    __syncthreads();
    #pragma unroll
    for (int kk = 0; kk < BK; kk += 32) {
      short8 af[FM], bfv[FN];
      #pragma unroll
      for (int i = 0; i < FM; ++i)
        af[i] = *(const short8*)(&As[(wm * WTM + i * 16 + lr) * LD + kk + kHalf]);
      #pragma unroll
      for (int j = 0; j < FN; ++j)
        bfv[j] = *(const short8*)(&Bs[(wn * WTN + j * 16 + lr) * LD + kk + kHalf]);
      #pragma unroll
      for (int i = 0; i < FM; ++i)
        #pragma unroll
        for (int j = 0; j < FN; ++j)
          acc[i][j] = __builtin_amdgcn_mfma_f32_16x16x32_bf16(af[i], bfv[j], acc[i][j], 0, 0, 0);
    }
    __syncthreads();
  }

  // epilogue: D row=(lane>>4)*4+r, col=lane&15 (m89-verified mapping)
  const int rBase = (lane >> 4) << 2;
  #pragma unroll
  for (int i = 0; i < FM; ++i) {
    #pragma unroll
    for (int j = 0; j < FN; ++j) {
      #pragma unroll
      for (int r = 0; r < 4; ++r) {
        int row = mBase + wm * WTM + i * 16 + rBase + r;
        int col = nBase + wn * WTN + j * 16 + lr;
        if (row < M && col < N) {
          float v = acc[i][j][r];
          size_t o = (size_t)row * N + col;
          if (EPI == EP_LOGIT) {
            v = 0.5f * v - 0.25f * aux1[row];
            ((_Float16*)Cout)[o] = (_Float16)v;
          } else if (EPI == EP_TANH) {
            v = tanhf(v + aux1[row]) * aux2[col];
            ((unsigned short*)Cout)[o] = f2bf(v);
          } else if (EPI == EP_BF16) {
            ((unsigned short*)Cout)[o] = f2bf(v);
          } else {
            ((float*)Cout)[o] = v;
          }
        }
      }
    }
  }
}

static inline int cdiv(int a, int b) { return (a + b - 1) / b; }

template<int EPI>
static void launch_gemm(int M, int N, int K, const unsigned short* A, const unsigned short* B,
                        void* C, const float* a1, const float* a2, hipStream_t s) {
  long b128   = (long)cdiv(M, 128) * cdiv(N, 128);
  long b12864 = (long)cdiv(M, 128) * cdiv(N, 64);
  if (b128 >= 192) {
    gemm_nt<128, 128, EPI><<<dim3(cdiv(M, 128), cdiv(N, 128)), 256, 0, s>>>(A, B, C, a1, a2, M, N, K);
  } else if (M >= 128 && b12864 >= 192) {
    gemm_nt<128, 64, EPI><<<dim3(cdiv(M, 128), cdiv(N, 64)), 256, 0, s>>>(A, B, C, a1, a2, M, N, K);
  } else {
    gemm_nt<64, 64, EPI><<<dim3(cdiv(M, 64), cdiv(N, 64)), 256, 0, s>>>(A, B, C, a1, a2, M, N, K);
  }
}

extern "C" void kernel_launch(void* const* d_in, const int* in_sizes, int n_in,
                              void* d_out, int out_size, void* d_ws, size_t ws_size,
                              hipStream_t stream) {
  const float* h0 = (const float*)d_in[0];
  const float* c1 = (const float*)d_in[1];
  const float* c2 = (const float*)d_in[2];
  const float* c3 = (const float*)d_in[3];
  const float* W1 = (const float*)d_in[4];
  const float* b1 = (const float*)d_in[5];
  const float* W2 = (const float*)d_in[6];
  const float* b2 = (const float*)d_in[7];
  const float* W3 = (const float*)d_in[8];
  const float* b3 = (const float*)d_in[9];

  const int d = 1024;
  const int N0 = 16384, N1 = 2048, N2 = 256, N3 = 32;

  char* w = (char*)d_ws;
  size_t off = 0;
  auto alloc = [&](size_t bytes) {
    void* p = w + off;
    off += (bytes + 255) & ~(size_t)255;
    return p;
  };
  unsigned short* hb  = (unsigned short*)alloc((size_t)N0 * d * 2);   // 32 MB
  unsigned short* cb1 = (unsigned short*)alloc((size_t)N1 * d * 2);
  unsigned short* cb2 = (unsigned short*)alloc((size_t)N2 * d * 2);
  unsigned short* cb3 = (unsigned short*)alloc((size_t)N3 * d * 2);
  float* cn1 = (float*)alloc((size_t)N1 * 4);
  float* cn2 = (float*)alloc((size_t)N2 * 4);
  float* cn3 = (float*)alloc((size_t)N3 * 4);
  unsigned short* Wb1 = (unsigned short*)alloc((size_t)d * d * 2);
  unsigned short* Wb2 = (unsigned short*)alloc((size_t)d * d * 2);
  unsigned short* Wb3 = (unsigned short*)alloc((size_t)d * d * 2);
  _Float16* ST = (_Float16*)alloc((size_t)N1 * N0 * 2);               // 64 MB, E overwrites in place
  unsigned short* tT = (unsigned short*)alloc((size_t)d * N0 * 2);    // 32 MB
  float* linv = (float*)alloc((size_t)N0 * 4);
  unsigned short* h1b = (unsigned short*)alloc((size_t)N1 * d * 2);
  unsigned short* h2b = (unsigned short*)alloc((size_t)N2 * d * 2);
  unsigned short* E = (unsigned short*)ST;
  (void)ws_size; (void)in_sizes; (void)n_in; (void)out_size;

  // ---- prep: bf16 casts + center norms ----
  cast_f32_bf16<<<cdiv(N0 * d, 1024), 256, 0, stream>>>(h0, hb, N0 * d);
  cast_f32_bf16<<<cdiv(d * d, 1024), 256, 0, stream>>>(W1, Wb1, d * d);
  cast_f32_bf16<<<cdiv(d * d, 1024), 256, 0, stream>>>(W2, Wb2, d * d);
  cast_f32_bf16<<<cdiv(d * d, 1024), 256, 0, stream>>>(W3, Wb3, d * d);
  prep_centers<<<N1, 256, 0, stream>>>(c1, cb1, cn1);
  prep_centers<<<N2, 256, 0, stream>>>(c2, cb2, cn2);
  prep_centers<<<N3, 256, 0, stream>>>(c3, cb3, cn3);

  // ---- level 1: h[16384] -> h1[2048] ----
  launch_gemm<EP_LOGIT>(N1, N0, d, cb1, hb, ST, cn1, nullptr, stream);
  softmax_col<<<N0 / 256, 256, 0, stream>>>(ST, linv, N1, N0);
  launch_gemm<EP_TANH>(d, N0, d, Wb1, hb, tT, b1, linv, stream);
  launch_gemm<EP_BF16>(N1, d, N0, E, tT, h1b, nullptr, nullptr, stream);

  // ---- level 2: h1[2048] -> h2[256] ----
  launch_gemm<EP_LOGIT>(N2, N1, d, cb2, h1b, ST, cn2, nullptr, stream);
  softmax_col<<<N1 / 256, 256, 0, stream>>>(ST, linv, N2, N1);
  launch_gemm<EP_TANH>(d, N1, d, Wb2, h1b, tT, b2, linv, stream);
  launch_gemm<EP_BF16>(N2, d, N1, E, tT, h2b, nullptr, nullptr, stream);

  // ---- level 3: h2[256] -> out[32][1024] fp32 ----
  launch_gemm<EP_LOGIT>(N3, N2, d, cb3, h2b, ST, cn3, nullptr, stream);
  softmax_col<<<N2 / 256, 256, 0, stream>>>(ST, linv, N3, N2);
  launch_gemm<EP_TANH>(d, N2, d, Wb3, h2b, tT, b3, linv, stream);
  launch_gemm<EP_F32>(N3, d, N2, E, tT, d_out, nullptr, nullptr, stream);
}

// Round 2
// 1262.038 us; speedup vs baseline: 1.9224x; 1.9224x over previous
//
#include <hip/hip_runtime.h>
#include <cmath>

typedef __attribute__((ext_vector_type(8))) short short8;
typedef __attribute__((ext_vector_type(4))) float floatx4;

__device__ __forceinline__ unsigned short f2bf(float f) {
  union { float f; unsigned u; } c; c.f = f;
  unsigned u = c.u;
  u += 0x7fffu + ((u >> 16) & 1u);
  return (unsigned short)(u >> 16);
}

// ---------------- elementwise cast fp32 -> bf16 (4/thread) ----------------
__global__ void cast_f32_bf16(const float* __restrict__ x, unsigned short* __restrict__ y, int n) {
  int i = (blockIdx.x * 256 + threadIdx.x) * 4;
  if (i >= n) return;
  float4 v = *(const float4*)(x + i);
  ushort4 o;
  o.x = f2bf(v.x); o.y = f2bf(v.y); o.z = f2bf(v.z); o.w = f2bf(v.w);
  *(ushort4*)(y + i) = o;
}

// ------------- centers: cast to bf16 + squared row norms (d=1024) -------------
__global__ void prep_centers(const float* __restrict__ c, unsigned short* __restrict__ cb,
                             float* __restrict__ cn) {
  int row = blockIdx.x, t = threadIdx.x;  // 256 threads, 4 elems each
  const float* cr = c + (size_t)row * 1024;
  float4 v = *(const float4*)(cr + t * 4);
  ushort4 o; o.x = f2bf(v.x); o.y = f2bf(v.y); o.z = f2bf(v.z); o.w = f2bf(v.w);
  *(ushort4*)(cb + (size_t)row * 1024 + t * 4) = o;
  float s = v.x * v.x + v.y * v.y + v.z * v.z + v.w * v.w;
  #pragma unroll
  for (int off = 32; off > 0; off >>= 1) s += __shfl_down(s, off, 64);
  __shared__ float ws[4];
  if ((t & 63) == 0) ws[t >> 6] = s;
  __syncthreads();
  if (t == 0) cn[row] = ws[0] + ws[1] + ws[2] + ws[3];
}

// ------------- parallel column softmax over ST[ncur][nprev] (fp16) -------------
// Pass A: partial max over a 64-row chunk per (blockIdx.y, col)
#define SM_CHUNK 64
__global__ void colmax_partial(const _Float16* __restrict__ ST, float* __restrict__ pmax,
                               int ncur, int nprev) {
  int col = blockIdx.x * 256 + threadIdx.x;          // nprev % 256 == 0
  int j0 = blockIdx.y * SM_CHUNK;
  int j1 = min(j0 + SM_CHUNK, ncur);
  float m = -1e30f;
  for (int j = j0; j < j1; ++j) {
    float x = (float)ST[(size_t)j * nprev + col];
    m = fmaxf(m, x);
  }
  pmax[(size_t)blockIdx.y * nprev + col] = m;
}

// Pass B: finalize max (redundant small re-reduce per block), exp in place -> bf16 E,
// partial sums per chunk.
__global__ void colexp_partial(_Float16* __restrict__ ST, const float* __restrict__ pmax,
                               float* __restrict__ psum, int nchunks, int ncur, int nprev) {
  int col = blockIdx.x * 256 + threadIdx.x;
  float m = -1e30f;
  for (int k = 0; k < nchunks; ++k)
    m = fmaxf(m, pmax[(size_t)k * nprev + col]);
  int j0 = blockIdx.y * SM_CHUNK;
  int j1 = min(j0 + SM_CHUNK, ncur);
  unsigned short* E = (unsigned short*)ST;
  float s = 0.f;
  for (int j = j0; j < j1; ++j) {
    size_t o = (size_t)j * nprev + col;
    float e = __expf((float)ST[o] - m);
    E[o] = f2bf(e);   // in place: same thread reads then writes same elem
    s += e;
  }
  psum[(size_t)blockIdx.y * nprev + col] = s;
}

// Pass C: linv = 1/sum
__global__ void colfin(const float* __restrict__ psum, float* __restrict__ linv,
                       int nchunks, int nprev) {
  int col = blockIdx.x * 256 + threadIdx.x;
  float s = 0.f;
  for (int k = 0; k < nchunks; ++k)
    s += psum[(size_t)k * nprev + col];
  linv[col] = 1.0f / s;
}

static inline int cdiv(int a, int b) { return (a + b - 1) / b; }

static void softmax_col_launch(_Float16* ST, float* pmax, float* psum, float* linv,
                               int ncur, int nprev, hipStream_t s) {
  int nchunks = cdiv(ncur, SM_CHUNK);
  dim3 g(nprev / 256, nchunks);
  colmax_partial<<<g, 256, 0, s>>>(ST, pmax, ncur, nprev);
  colexp_partial<<<g, 256, 0, s>>>(ST, pmax, psum, nchunks, ncur, nprev);
  colfin<<<nprev / 256, 256, 0, s>>>(psum, linv, nchunks, nprev);
}

// ---------------- NT bf16 MFMA GEMM: C[M][N] = A[M][K] * B[N][K]^T ----------------
enum { EP_LOGIT = 0, EP_TANH = 1, EP_BF16 = 2, EP_F32 = 3 };

template<int BM, int BN, int EPI>
__launch_bounds__(256, 2)
__global__ void gemm_nt(const unsigned short* __restrict__ A,
                        const unsigned short* __restrict__ B,
                        void* __restrict__ Cout,
                        const float* __restrict__ aux1,   // cn[M] or bias[M]
                        const float* __restrict__ aux2,   // linv[N]
                        int M, int N, int K) {
  constexpr int BK = 64, PAD = 8, LD = BK + PAD;  // pad keeps 16B alignment, staggers banks
  constexpr int WTM = BM / 2, WTN = BN / 2;
  constexpr int FM = WTM / 16, FN = WTN / 16;
  __shared__ __align__(16) unsigned short As[BM * LD];
  __shared__ __align__(16) unsigned short Bs[BN * LD];
  const int tid  = threadIdx.x;
  const int lane = tid & 63;
  const int wave = tid >> 6;
  const int wm = wave >> 1, wn = wave & 1;
  const int mBase = blockIdx.x * BM, nBase = blockIdx.y * BN;
  const int lr    = lane & 15;           // fragment row (A: m, B: n)
  const int kHalf = (lane >> 4) << 3;    // fragment k offset: 0,8,16,24

  floatx4 acc[FM][FN] = {};
  constexpr int AV = BM * BK / (256 * 8);
  constexpr int BV = BN * BK / (256 * 8);

  for (int k0 = 0; k0 < K; k0 += BK) {   // K % 64 == 0 for all call sites
    #pragma unroll
    for (int v = 0; v < AV; ++v) {
      int idx = v * 256 + tid;
      int r = idx >> 3, cc = (idx & 7) << 3;
      int gm = mBase + r;
      short8 val = {0, 0, 0, 0, 0, 0, 0, 0};
      if (gm < M) val = *(const short8*)(A + (size_t)gm * K + k0 + cc);
      *(short8*)(&As[r * LD + cc]) = val;
    }
    #pragma unroll
    for (int v = 0; v < BV; ++v) {
      int idx = v * 256 + tid;
      int r = idx >> 3, cc = (idx & 7) << 3;
      int gn = nBase + r;
      short8 val = {0, 0, 0, 0, 0, 0, 0, 0};
      if (gn < N) val = *(const short8*)(B + (size_t)gn * K + k0 + cc);
      *(short8*)(&Bs[r * LD + cc]) = val;
    }
    __syncthreads();
    #pragma unroll
    for (int kk = 0; kk < BK; kk += 32) {
      short8 af[FM], bfv[FN];
      #pragma unroll
      for (int i = 0; i < FM; ++i)
        af[i] = *(const short8*)(&As[(wm * WTM + i * 16 + lr) * LD + kk + kHalf]);
      #pragma unroll
      for (int j = 0; j < FN; ++j)
        bfv[j] = *(const short8*)(&Bs[(wn * WTN + j * 16 + lr) * LD + kk + kHalf]);
      #pragma unroll
      for (int i = 0; i < FM; ++i)
        #pragma unroll
        for (int j = 0; j < FN; ++j)
          acc[i][j] = __builtin_amdgcn_mfma_f32_16x16x32_bf16(af[i], bfv[j], acc[i][j], 0, 0, 0);
    }
    __syncthreads();
  }

  // epilogue: D row=(lane>>4)*4+r, col=lane&15 (m89-verified mapping)
  const int rBase = (lane >> 4) << 2;
  #pragma unroll
  for (int i = 0; i < FM; ++i) {
    #pragma unroll
    for (int j = 0; j < FN; ++j) {
      #pragma unroll
      for (int r = 0; r < 4; ++r) {
        int row = mBase + wm * WTM + i * 16 + rBase + r;
        int col = nBase + wn * WTN + j * 16 + lr;
        if (row < M && col < N) {
          float v = acc[i][j][r];
          size_t o = (size_t)row * N + col;
          if (EPI == EP_LOGIT) {
            v = 0.5f * v - 0.25f * aux1[row];
            ((_Float16*)Cout)[o] = (_Float16)v;
          } else if (EPI == EP_TANH) {
            v = tanhf(v + aux1[row]) * aux2[col];
            ((unsigned short*)Cout)[o] = f2bf(v);
          } else if (EPI == EP_BF16) {
            ((unsigned short*)Cout)[o] = f2bf(v);
          } else {
            ((float*)Cout)[o] = v;
          }
        }
      }
    }
  }
}

template<int EPI>
static void launch_gemm(int M, int N, int K, const unsigned short* A, const unsigned short* B,
                        void* C, const float* a1, const float* a2, hipStream_t s) {
  long b128   = (long)cdiv(M, 128) * cdiv(N, 128);
  long b12864 = (long)cdiv(M, 128) * cdiv(N, 64);
  if (b128 >= 192) {
    gemm_nt<128, 128, EPI><<<dim3(cdiv(M, 128), cdiv(N, 128)), 256, 0, s>>>(A, B, C, a1, a2, M, N, K);
  } else if (M >= 128 && b12864 >= 192) {
    gemm_nt<128, 64, EPI><<<dim3(cdiv(M, 128), cdiv(N, 64)), 256, 0, s>>>(A, B, C, a1, a2, M, N, K);
  } else {
    gemm_nt<64, 64, EPI><<<dim3(cdiv(M, 64), cdiv(N, 64)), 256, 0, s>>>(A, B, C, a1, a2, M, N, K);
  }
}

extern "C" void kernel_launch(void* const* d_in, const int* in_sizes, int n_in,
                              void* d_out, int out_size, void* d_ws, size_t ws_size,
                              hipStream_t stream) {
  const float* h0 = (const float*)d_in[0];
  const float* c1 = (const float*)d_in[1];
  const float* c2 = (const float*)d_in[2];
  const float* c3 = (const float*)d_in[3];
  const float* W1 = (const float*)d_in[4];
  const float* b1 = (const float*)d_in[5];
  const float* W2 = (const float*)d_in[6];
  const float* b2 = (const float*)d_in[7];
  const float* W3 = (const float*)d_in[8];
  const float* b3 = (const float*)d_in[9];

  const int d = 1024;
  const int N0 = 16384, N1 = 2048, N2 = 256, N3 = 32;

  char* w = (char*)d_ws;
  size_t off = 0;
  auto alloc = [&](size_t bytes) {
    void* p = w + off;
    off += (bytes + 255) & ~(size_t)255;
    return p;
  };
  unsigned short* hb  = (unsigned short*)alloc((size_t)N0 * d * 2);   // 32 MB
  unsigned short* cb1 = (unsigned short*)alloc((size_t)N1 * d * 2);
  unsigned short* cb2 = (unsigned short*)alloc((size_t)N2 * d * 2);
  unsigned short* cb3 = (unsigned short*)alloc((size_t)N3 * d * 2);
  float* cn1 = (float*)alloc((size_t)N1 * 4);
  float* cn2 = (float*)alloc((size_t)N2 * 4);
  float* cn3 = (float*)alloc((size_t)N3 * 4);
  unsigned short* Wb1 = (unsigned short*)alloc((size_t)d * d * 2);
  unsigned short* Wb2 = (unsigned short*)alloc((size_t)d * d * 2);
  unsigned short* Wb3 = (unsigned short*)alloc((size_t)d * d * 2);
  _Float16* ST = (_Float16*)alloc((size_t)N1 * N0 * 2);               // 64 MB, E overwrites in place
  unsigned short* tT = (unsigned short*)alloc((size_t)d * N0 * 2);    // 32 MB
  float* linv = (float*)alloc((size_t)N0 * 4);
  float* pmax = (float*)alloc((size_t)32 * N0 * 4);                   // 2 MB partial maxes
  float* psum = (float*)alloc((size_t)32 * N0 * 4);                   // 2 MB partial sums
  unsigned short* h1b = (unsigned short*)alloc((size_t)N1 * d * 2);
  unsigned short* h2b = (unsigned short*)alloc((size_t)N2 * d * 2);
  unsigned short* E = (unsigned short*)ST;
  (void)ws_size; (void)in_sizes; (void)n_in; (void)out_size;

  // ---- prep: bf16 casts + center norms ----
  cast_f32_bf16<<<cdiv(N0 * d, 1024), 256, 0, stream>>>(h0, hb, N0 * d);
  cast_f32_bf16<<<cdiv(d * d, 1024), 256, 0, stream>>>(W1, Wb1, d * d);
  cast_f32_bf16<<<cdiv(d * d, 1024), 256, 0, stream>>>(W2, Wb2, d * d);
  cast_f32_bf16<<<cdiv(d * d, 1024), 256, 0, stream>>>(W3, Wb3, d * d);
  prep_centers<<<N1, 256, 0, stream>>>(c1, cb1, cn1);
  prep_centers<<<N2, 256, 0, stream>>>(c2, cb2, cn2);
  prep_centers<<<N3, 256, 0, stream>>>(c3, cb3, cn3);

  // ---- level 1: h[16384] -> h1[2048] ----
  launch_gemm<EP_LOGIT>(N1, N0, d, cb1, hb, ST, cn1, nullptr, stream);
  softmax_col_launch(ST, pmax, psum, linv, N1, N0, stream);
  launch_gemm<EP_TANH>(d, N0, d, Wb1, hb, tT, b1, linv, stream);
  launch_gemm<EP_BF16>(N1, d, N0, E, tT, h1b, nullptr, nullptr, stream);

  // ---- level 2: h1[2048] -> h2[256] ----
  launch_gemm<EP_LOGIT>(N2, N1, d, cb2, h1b, ST, cn2, nullptr, stream);
  softmax_col_launch(ST, pmax, psum, linv, N2, N1, stream);
  launch_gemm<EP_TANH>(d, N1, d, Wb2, h1b, tT, b2, linv, stream);
  launch_gemm<EP_BF16>(N2, d, N1, E, tT, h2b, nullptr, nullptr, stream);

  // ---- level 3: h2[256] -> out[32][1024] fp32 ----
  launch_gemm<EP_LOGIT>(N3, N2, d, cb3, h2b, ST, cn3, nullptr, stream);
  softmax_col_launch(ST, pmax, psum, linv, N3, N2, stream);
  launch_gemm<EP_TANH>(d, N2, d, Wb3, h2b, tT, b3, linv, stream);
  launch_gemm<EP_F32>(N3, d, N2, E, tT, d_out, nullptr, nullptr, stream);
}

// Round 3
// 754.502 us; speedup vs baseline: 3.2155x; 1.6727x over previous
//
#include <hip/hip_runtime.h>
#include <cmath>

typedef __attribute__((ext_vector_type(8))) short short8;
typedef __attribute__((ext_vector_type(4))) float floatx4;

__device__ __forceinline__ unsigned short f2bf(float f) {
  union { float f; unsigned u; } c; c.f = f;
  unsigned u = c.u;
  u += 0x7fffu + ((u >> 16) & 1u);
  return (unsigned short)(u >> 16);
}

// ---------------- elementwise cast fp32 -> bf16 (4/thread) ----------------
__global__ void cast_f32_bf16(const float* __restrict__ x, unsigned short* __restrict__ y, int n) {
  int i = (blockIdx.x * 256 + threadIdx.x) * 4;
  if (i >= n) return;
  float4 v = *(const float4*)(x + i);
  ushort4 o;
  o.x = f2bf(v.x); o.y = f2bf(v.y); o.z = f2bf(v.z); o.w = f2bf(v.w);
  *(ushort4*)(y + i) = o;
}

// ------------- centers: cast to bf16 + squared row norms (d=1024) -------------
__global__ void prep_centers(const float* __restrict__ c, unsigned short* __restrict__ cb,
                             float* __restrict__ cn) {
  int row = blockIdx.x, t = threadIdx.x;  // 256 threads, 4 elems each
  const float* cr = c + (size_t)row * 1024;
  float4 v = *(const float4*)(cr + t * 4);
  ushort4 o; o.x = f2bf(v.x); o.y = f2bf(v.y); o.z = f2bf(v.z); o.w = f2bf(v.w);
  *(ushort4*)(cb + (size_t)row * 1024 + t * 4) = o;
  float s = v.x * v.x + v.y * v.y + v.z * v.z + v.w * v.w;
  #pragma unroll
  for (int off = 32; off > 0; off >>= 1) s += __shfl_down(s, off, 64);
  __shared__ float ws[4];
  if ((t & 63) == 0) ws[t >> 6] = s;
  __syncthreads();
  if (t == 0) cn[row] = ws[0] + ws[1] + ws[2] + ws[3];
}

// ------------- parallel column softmax over ST[ncur][nprev] (fp16) -------------
#define SM_CHUNK 64
__global__ void colmax_partial(const _Float16* __restrict__ ST, float* __restrict__ pmax,
                               int ncur, int nprev) {
  int col = blockIdx.x * 256 + threadIdx.x;          // nprev % 256 == 0
  int j0 = blockIdx.y * SM_CHUNK;
  int j1 = min(j0 + SM_CHUNK, ncur);
  float m = -1e30f;
  for (int j = j0; j < j1; ++j) {
    float x = (float)ST[(size_t)j * nprev + col];
    m = fmaxf(m, x);
  }
  pmax[(size_t)blockIdx.y * nprev + col] = m;
}

__global__ void colexp_partial(_Float16* __restrict__ ST, const float* __restrict__ pmax,
                               float* __restrict__ psum, int nchunks, int ncur, int nprev) {
  int col = blockIdx.x * 256 + threadIdx.x;
  float m = -1e30f;
  for (int k = 0; k < nchunks; ++k)
    m = fmaxf(m, pmax[(size_t)k * nprev + col]);
  int j0 = blockIdx.y * SM_CHUNK;
  int j1 = min(j0 + SM_CHUNK, ncur);
  unsigned short* E = (unsigned short*)ST;
  float s = 0.f;
  for (int j = j0; j < j1; ++j) {
    size_t o = (size_t)j * nprev + col;
    float e = __expf((float)ST[o] - m);
    E[o] = f2bf(e);   // in place: same thread reads then writes same elem
    s += e;
  }
  psum[(size_t)blockIdx.y * nprev + col] = s;
}

__global__ void colfin(const float* __restrict__ psum, float* __restrict__ linv,
                       int nchunks, int nprev) {
  int col = blockIdx.x * 256 + threadIdx.x;
  float s = 0.f;
  for (int k = 0; k < nchunks; ++k)
    s += psum[(size_t)k * nprev + col];
  linv[col] = 1.0f / s;
}

static inline int cdiv(int a, int b) { return (a + b - 1) / b; }

static void softmax_col_launch(_Float16* ST, float* pmax, float* psum, float* linv,
                               int ncur, int nprev, hipStream_t s) {
  int nchunks = cdiv(ncur, SM_CHUNK);
  dim3 g(nprev / 256, nchunks);
  colmax_partial<<<g, 256, 0, s>>>(ST, pmax, ncur, nprev);
  colexp_partial<<<g, 256, 0, s>>>(ST, pmax, psum, nchunks, ncur, nprev);
  colfin<<<nprev / 256, 256, 0, s>>>(psum, linv, nchunks, nprev);
}

// ---------------- split-K reduce: out_bf16[i] = sum_s part[s][i] ----------------
__global__ void reduce_parts(const float* __restrict__ part, unsigned short* __restrict__ out,
                             int mn, int S) {
  int i = (blockIdx.x * 256 + threadIdx.x) * 4;
  if (i >= mn) return;
  float4 a = *(const float4*)(part + i);
  for (int s = 1; s < S; ++s) {
    float4 v = *(const float4*)(part + (size_t)s * mn + i);
    a.x += v.x; a.y += v.y; a.z += v.z; a.w += v.w;
  }
  ushort4 o;
  o.x = f2bf(a.x); o.y = f2bf(a.y); o.z = f2bf(a.z); o.w = f2bf(a.w);
  *(ushort4*)(out + i) = o;
}

// ---------------- NT bf16 MFMA GEMM: C[M][N] = A[M][K] * B[N][K]^T ----------------
// Split-K: blockIdx.z selects a K-range of length kLen; EP_PART writes fp32 partials.
enum { EP_LOGIT = 0, EP_TANH = 1, EP_BF16 = 2, EP_F32 = 3, EP_PART = 4 };

template<int BM, int BN, int EPI>
__launch_bounds__(256, 4)
__global__ void gemm_nt(const unsigned short* __restrict__ A,
                        const unsigned short* __restrict__ B,
                        void* __restrict__ Cout,
                        const float* __restrict__ aux1,   // cn[M] or bias[M]
                        const float* __restrict__ aux2,   // linv[N]
                        int M, int N, int K, int kLen) {
  constexpr int BK = 64, PAD = 8, LD = BK + PAD;  // pad keeps 16B alignment, staggers banks
  constexpr int WTM = BM / 2, WTN = BN / 2;
  constexpr int FM = WTM / 16, FN = WTN / 16;
  __shared__ __align__(16) unsigned short As[BM * LD];
  __shared__ __align__(16) unsigned short Bs[BN * LD];
  const int tid  = threadIdx.x;
  const int lane = tid & 63;
  const int wave = tid >> 6;
  const int wm = wave >> 1, wn = wave & 1;
  const int mBase = blockIdx.x * BM, nBase = blockIdx.y * BN;
  const int kBase = blockIdx.z * kLen;
  const int lr    = lane & 15;           // fragment row (A: m, B: n)
  const int kHalf = (lane >> 4) << 3;    // fragment k offset: 0,8,16,24

  floatx4 acc[FM][FN] = {};
  constexpr int AV = BM * BK / (256 * 8);
  constexpr int BV = BN * BK / (256 * 8);

  for (int k0 = kBase; k0 < kBase + kLen; k0 += BK) {   // kLen % 64 == 0 at all call sites
    #pragma unroll
    for (int v = 0; v < AV; ++v) {
      int idx = v * 256 + tid;
      int r = idx >> 3, cc = (idx & 7) << 3;
      int gm = mBase + r;
      short8 val = {0, 0, 0, 0, 0, 0, 0, 0};
      if (gm < M) val = *(const short8*)(A + (size_t)gm * K + k0 + cc);
      *(short8*)(&As[r * LD + cc]) = val;
    }
    #pragma unroll
    for (int v = 0; v < BV; ++v) {
      int idx = v * 256 + tid;
      int r = idx >> 3, cc = (idx & 7) << 3;
      int gn = nBase + r;
      short8 val = {0, 0, 0, 0, 0, 0, 0, 0};
      if (gn < N) val = *(const short8*)(B + (size_t)gn * K + k0 + cc);
      *(short8*)(&Bs[r * LD + cc]) = val;
    }
    __syncthreads();
    #pragma unroll
    for (int kk = 0; kk < BK; kk += 32) {
      short8 af[FM], bfv[FN];
      #pragma unroll
      for (int i = 0; i < FM; ++i)
        af[i] = *(const short8*)(&As[(wm * WTM + i * 16 + lr) * LD + kk + kHalf]);
      #pragma unroll
      for (int j = 0; j < FN; ++j)
        bfv[j] = *(const short8*)(&Bs[(wn * WTN + j * 16 + lr) * LD + kk + kHalf]);
      #pragma unroll
      for (int i = 0; i < FM; ++i)
        #pragma unroll
        for (int j = 0; j < FN; ++j)
          acc[i][j] = __builtin_amdgcn_mfma_f32_16x16x32_bf16(af[i], bfv[j], acc[i][j], 0, 0, 0);
    }
    __syncthreads();
  }

  // epilogue: D row=(lane>>4)*4+r, col=lane&15 (m89-verified mapping)
  const int rBase = (lane >> 4) << 2;
  #pragma unroll
  for (int i = 0; i < FM; ++i) {
    #pragma unroll
    for (int j = 0; j < FN; ++j) {
      #pragma unroll
      for (int r = 0; r < 4; ++r) {
        int row = mBase + wm * WTM + i * 16 + rBase + r;
        int col = nBase + wn * WTN + j * 16 + lr;
        if (row < M && col < N) {
          float v = acc[i][j][r];
          size_t o = (size_t)row * N + col;
          if (EPI == EP_LOGIT) {
            v = 0.5f * v - 0.25f * aux1[row];
            ((_Float16*)Cout)[o] = (_Float16)v;
          } else if (EPI == EP_TANH) {
            v = tanhf(v + aux1[row]) * aux2[col];
            ((unsigned short*)Cout)[o] = f2bf(v);
          } else if (EPI == EP_BF16) {
            ((unsigned short*)Cout)[o] = f2bf(v);
          } else if (EPI == EP_PART) {
            ((float*)Cout)[(size_t)blockIdx.z * M * N + o] = v;
          } else {
            ((float*)Cout)[o] = v;
          }
        }
      }
    }
  }
}

template<int EPI>
static void launch_gemm(int M, int N, int K, const unsigned short* A, const unsigned short* B,
                        void* C, const float* a1, const float* a2, hipStream_t s) {
  long b128   = (long)cdiv(M, 128) * cdiv(N, 128);
  long b12864 = (long)cdiv(M, 128) * cdiv(N, 64);
  if (b128 >= 192) {
    gemm_nt<128, 128, EPI><<<dim3(cdiv(M, 128), cdiv(N, 128)), 256, 0, s>>>(A, B, C, a1, a2, M, N, K, K);
  } else if (M >= 128 && b12864 >= 192) {
    gemm_nt<128, 64, EPI><<<dim3(cdiv(M, 128), cdiv(N, 64)), 256, 0, s>>>(A, B, C, a1, a2, M, N, K, K);
  } else {
    gemm_nt<64, 64, EPI><<<dim3(cdiv(M, 64), cdiv(N, 64)), 256, 0, s>>>(A, B, C, a1, a2, M, N, K, K);
  }
}

// split-K path for deep-K, small-MN GEMMs; writes fp32 partials then reduces to bf16
static void launch_gemm_splitk(int M, int N, int K, int S,
                               const unsigned short* A, const unsigned short* B,
                               float* Cpart, unsigned short* Cout, hipStream_t s) {
  int kLen = K / S;
  if (M >= 128 && N >= 128) {
    gemm_nt<128, 128, EP_PART><<<dim3(cdiv(M, 128), cdiv(N, 128), S), 256, 0, s>>>(
        A, B, Cpart, nullptr, nullptr, M, N, K, kLen);
  } else {
    gemm_nt<64, 64, EP_PART><<<dim3(cdiv(M, 64), cdiv(N, 64), S), 256, 0, s>>>(
        A, B, Cpart, nullptr, nullptr, M, N, K, kLen);
  }
  int mn = M * N;
  reduce_parts<<<cdiv(mn, 1024), 256, 0, s>>>(Cpart, Cout, mn, S);
}

extern "C" void kernel_launch(void* const* d_in, const int* in_sizes, int n_in,
                              void* d_out, int out_size, void* d_ws, size_t ws_size,
                              hipStream_t stream) {
  const float* h0 = (const float*)d_in[0];
  const float* c1 = (const float*)d_in[1];
  const float* c2 = (const float*)d_in[2];
  const float* c3 = (const float*)d_in[3];
  const float* W1 = (const float*)d_in[4];
  const float* b1 = (const float*)d_in[5];
  const float* W2 = (const float*)d_in[6];
  const float* b2 = (const float*)d_in[7];
  const float* W3 = (const float*)d_in[8];
  const float* b3 = (const float*)d_in[9];

  const int d = 1024;
  const int N0 = 16384, N1 = 2048, N2 = 256, N3 = 32;

  char* w = (char*)d_ws;
  size_t off = 0;
  auto alloc = [&](size_t bytes) {
    void* p = w + off;
    off += (bytes + 255) & ~(size_t)255;
    return p;
  };
  unsigned short* hb  = (unsigned short*)alloc((size_t)N0 * d * 2);   // 32 MB
  unsigned short* cb1 = (unsigned short*)alloc((size_t)N1 * d * 2);
  unsigned short* cb2 = (unsigned short*)alloc((size_t)N2 * d * 2);
  unsigned short* cb3 = (unsigned short*)alloc((size_t)N3 * d * 2);
  float* cn1 = (float*)alloc((size_t)N1 * 4);
  float* cn2 = (float*)alloc((size_t)N2 * 4);
  float* cn3 = (float*)alloc((size_t)N3 * 4);
  unsigned short* Wb1 = (unsigned short*)alloc((size_t)d * d * 2);
  unsigned short* Wb2 = (unsigned short*)alloc((size_t)d * d * 2);
  unsigned short* Wb3 = (unsigned short*)alloc((size_t)d * d * 2);
  _Float16* ST = (_Float16*)alloc((size_t)N1 * N0 * 2);               // 64 MB, E overwrites in place
  unsigned short* tT = (unsigned short*)alloc((size_t)d * N0 * 2);    // 32 MB
  float* linv = (float*)alloc((size_t)N0 * 4);
  float* pmax = (float*)alloc((size_t)32 * N0 * 4);                   // 2 MB partial maxes
  float* psum = (float*)alloc((size_t)32 * N0 * 4);                   // 2 MB partial sums
  unsigned short* h1b = (unsigned short*)alloc((size_t)N1 * d * 2);
  unsigned short* h2b = (unsigned short*)alloc((size_t)N2 * d * 2);
  float* Cpart = (float*)alloc((size_t)8 * N1 * d * 4);               // 64 MB split-K partials
  unsigned short* E = (unsigned short*)ST;
  (void)ws_size; (void)in_sizes; (void)n_in; (void)out_size;

  // ---- prep: bf16 casts + center norms ----
  cast_f32_bf16<<<cdiv(N0 * d, 1024), 256, 0, stream>>>(h0, hb, N0 * d);
  cast_f32_bf16<<<cdiv(d * d, 1024), 256, 0, stream>>>(W1, Wb1, d * d);
  cast_f32_bf16<<<cdiv(d * d, 1024), 256, 0, stream>>>(W2, Wb2, d * d);
  cast_f32_bf16<<<cdiv(d * d, 1024), 256, 0, stream>>>(W3, Wb3, d * d);
  prep_centers<<<N1, 256, 0, stream>>>(c1, cb1, cn1);
  prep_centers<<<N2, 256, 0, stream>>>(c2, cb2, cn2);
  prep_centers<<<N3, 256, 0, stream>>>(c3, cb3, cn3);

  // ---- level 1: h[16384] -> h1[2048] ----
  launch_gemm<EP_LOGIT>(N1, N0, d, cb1, hb, ST, cn1, nullptr, stream);
  softmax_col_launch(ST, pmax, psum, linv, N1, N0, stream);
  launch_gemm<EP_TANH>(d, N0, d, Wb1, hb, tT, b1, linv, stream);
  launch_gemm_splitk(N1, d, N0, 8, E, tT, Cpart, h1b, stream);   // grid 16x8x8 = 1024 blocks

  // ---- level 2: h1[2048] -> h2[256] ----
  launch_gemm<EP_LOGIT>(N2, N1, d, cb2, h1b, ST, cn2, nullptr, stream);
  softmax_col_launch(ST, pmax, psum, linv, N2, N1, stream);
  launch_gemm<EP_TANH>(d, N1, d, Wb2, h1b, tT, b2, linv, stream);
  launch_gemm_splitk(N2, d, N1, 4, E, tT, Cpart, h2b, stream);   // grid 4x16x4 = 256 blocks

  // ---- level 3: h2[256] -> out[32][1024] fp32 ----
  launch_gemm<EP_LOGIT>(N3, N2, d, cb3, h2b, ST, cn3, nullptr, stream);
  softmax_col_launch(ST, pmax, psum, linv, N3, N2, stream);
  launch_gemm<EP_TANH>(d, N2, d, Wb3, h2b, tT, b3, linv, stream);
  launch_gemm<EP_F32>(N3, d, N2, E, tT, d_out, nullptr, nullptr, stream);
}

// Round 4
// 576.380 us; speedup vs baseline: 4.2092x; 1.3090x over previous
//
#include <hip/hip_runtime.h>
#include <cmath>

typedef __attribute__((ext_vector_type(8))) short short8;
typedef __attribute__((ext_vector_type(4))) float floatx4;

#define GLOAD_LDS16(gp, lp)                                            \
  __builtin_amdgcn_global_load_lds(                                    \
      (const __attribute__((address_space(1))) void*)(gp),             \
      (__attribute__((address_space(3))) void*)(lp), 16, 0, 0)

__device__ __forceinline__ unsigned short f2bf(float f) {
  union { float f; unsigned u; } c; c.f = f;
  unsigned u = c.u;
  u += 0x7fffu + ((u >> 16) & 1u);
  return (unsigned short)(u >> 16);
}

// ---------------- elementwise cast fp32 -> bf16 (4/thread) ----------------
__global__ void cast_f32_bf16(const float* __restrict__ x, unsigned short* __restrict__ y, int n) {
  int i = (blockIdx.x * 256 + threadIdx.x) * 4;
  if (i >= n) return;
  float4 v = *(const float4*)(x + i);
  ushort4 o;
  o.x = f2bf(v.x); o.y = f2bf(v.y); o.z = f2bf(v.z); o.w = f2bf(v.w);
  *(ushort4*)(y + i) = o;
}

// ------------- centers: cast to bf16 + squared row norms (d=1024) -------------
__global__ void prep_centers(const float* __restrict__ c, unsigned short* __restrict__ cb,
                             float* __restrict__ cn) {
  int row = blockIdx.x, t = threadIdx.x;  // 256 threads, 4 elems each
  const float* cr = c + (size_t)row * 1024;
  float4 v = *(const float4*)(cr + t * 4);
  ushort4 o; o.x = f2bf(v.x); o.y = f2bf(v.y); o.z = f2bf(v.z); o.w = f2bf(v.w);
  *(ushort4*)(cb + (size_t)row * 1024 + t * 4) = o;
  float s = v.x * v.x + v.y * v.y + v.z * v.z + v.w * v.w;
  #pragma unroll
  for (int off = 32; off > 0; off >>= 1) s += __shfl_down(s, off, 64);
  __shared__ float ws[4];
  if ((t & 63) == 0) ws[t >> 6] = s;
  __syncthreads();
  if (t == 0) cn[row] = ws[0] + ws[1] + ws[2] + ws[3];
}

// ------------- parallel column softmax over ST[ncur][nprev] (fp16) -------------
#define SM_CHUNK 64
__global__ void colmax_partial(const _Float16* __restrict__ ST, float* __restrict__ pmax,
                               int ncur, int nprev) {
  int col = blockIdx.x * 256 + threadIdx.x;          // nprev % 256 == 0
  int j0 = blockIdx.y * SM_CHUNK;
  int j1 = min(j0 + SM_CHUNK, ncur);
  float m = -1e30f;
  for (int j = j0; j < j1; ++j) {
    float x = (float)ST[(size_t)j * nprev + col];
    m = fmaxf(m, x);
  }
  pmax[(size_t)blockIdx.y * nprev + col] = m;
}

__global__ void colexp_partial(_Float16* __restrict__ ST, const float* __restrict__ pmax,
                               float* __restrict__ psum, int nchunks, int ncur, int nprev) {
  int col = blockIdx.x * 256 + threadIdx.x;
  float m = -1e30f;
  for (int k = 0; k < nchunks; ++k)
    m = fmaxf(m, pmax[(size_t)k * nprev + col]);
  int j0 = blockIdx.y * SM_CHUNK;
  int j1 = min(j0 + SM_CHUNK, ncur);
  unsigned short* E = (unsigned short*)ST;
  float s = 0.f;
  for (int j = j0; j < j1; ++j) {
    size_t o = (size_t)j * nprev + col;
    float e = __expf((float)ST[o] - m);
    E[o] = f2bf(e);   // in place: same thread reads then writes same elem
    s += e;
  }
  psum[(size_t)blockIdx.y * nprev + col] = s;
}

__global__ void colfin(const float* __restrict__ psum, float* __restrict__ linv,
                       int nchunks, int nprev) {
  int col = blockIdx.x * 256 + threadIdx.x;
  float s = 0.f;
  for (int k = 0; k < nchunks; ++k)
    s += psum[(size_t)k * nprev + col];
  linv[col] = 1.0f / s;
}

static inline int cdiv(int a, int b) { return (a + b - 1) / b; }

static void softmax_col_launch(_Float16* ST, float* pmax, float* psum, float* linv,
                               int ncur, int nprev, hipStream_t s) {
  int nchunks = cdiv(ncur, SM_CHUNK);
  dim3 g(nprev / 256, nchunks);
  colmax_partial<<<g, 256, 0, s>>>(ST, pmax, ncur, nprev);
  colexp_partial<<<g, 256, 0, s>>>(ST, pmax, psum, nchunks, ncur, nprev);
  colfin<<<nprev / 256, 256, 0, s>>>(psum, linv, nchunks, nprev);
}

// ---------------- split-K reduce: out_bf16[i] = sum_s part[s][i] ----------------
__global__ void reduce_parts(const float* __restrict__ part, unsigned short* __restrict__ out,
                             int mn, int S) {
  int i = (blockIdx.x * 256 + threadIdx.x) * 4;
  if (i >= mn) return;
  float4 a = *(const float4*)(part + i);
  for (int s = 1; s < S; ++s) {
    float4 v = *(const float4*)(part + (size_t)s * mn + i);
    a.x += v.x; a.y += v.y; a.z += v.z; a.w += v.w;
  }
  ushort4 o;
  o.x = f2bf(a.x); o.y = f2bf(a.y); o.z = f2bf(a.z); o.w = f2bf(a.w);
  *(ushort4*)(out + i) = o;
}

// ---------------- NT bf16 MFMA GEMM: C[M][N] = A[M][K] * B[N][K]^T ----------------
// global_load_lds (16B) staging, XOR-swizzled LDS layout:
//   LDS chunk-pos p (16B) of row r holds global K-chunk p ^ (r&7).
// Staging: lane L of wave w writes bytes [base + L*16]; it reads global chunk
//   (L%8) ^ (L/8) of row rowBase + L/8  -> swizzle holds since rowBase%8==0.
// Reads: chunk q of row r sits at LDS pos q ^ (r&7) -> 8 consecutive lanes hit
//   8 distinct 16B quads = all 32 banks, conflict-free.
enum { EP_LOGIT = 0, EP_TANH = 1, EP_BF16 = 2, EP_F32 = 3, EP_PART = 4 };

template<int BM, int BN, int EPI>
__launch_bounds__(256, 4)
__global__ void gemm_nt(const unsigned short* __restrict__ A,
                        const unsigned short* __restrict__ B,
                        void* __restrict__ Cout,
                        const float* __restrict__ aux1,   // cn[M] or bias[M]
                        const float* __restrict__ aux2,   // linv[N]
                        int M, int N, int K, int kLen) {
  constexpr int BK = 64;                 // 128 B/row, unpadded (required by global_load_lds)
  constexpr int WTM = BM / 2, WTN = BN / 2;
  constexpr int FM = WTM / 16, FN = WTN / 16;
  __shared__ __align__(16) unsigned short As[BM * BK];
  __shared__ __align__(16) unsigned short Bs[BN * BK];
  const int tid  = threadIdx.x;
  const int lane = tid & 63;
  const int wave = tid >> 6;
  const int wm = wave >> 1, wn = wave & 1;
  const int mBase = blockIdx.x * BM, nBase = blockIdx.y * BN;
  const int kBase = blockIdx.z * kLen;
  const int lr    = lane & 15;           // fragment row (A: m, B: n)
  const int kHalf = (lane >> 4) << 3;    // fragment k offset: 0,8,16,24

  // staging geometry (per wave, per v-step: 64 lanes x 16B = 8 rows)
  const int srOff   = lane >> 3;                       // row within 8-row group
  const int schunk  = (lane & 7) ^ srOff;              // swizzled global K-chunk
  floatx4 acc[FM][FN] = {};
  constexpr int AV = BM * BK / (256 * 8);              // v-steps for A (32 rows each)
  constexpr int BV = BN * BK / (256 * 8);

  for (int k0 = kBase; k0 < kBase + kLen; k0 += BK) {  // kLen % 64 == 0 at all call sites
    #pragma unroll
    for (int v = 0; v < AV; ++v) {
      int rowBase = v * 32 + wave * 8;
      int gm = mBase + rowBase + srOff;
      if (gm >= M) gm = M - 1;                         // clamp: garbage only feeds discarded rows
      GLOAD_LDS16(A + (size_t)gm * K + k0 + schunk * 8, &As[rowBase * BK]);
    }
    #pragma unroll
    for (int v = 0; v < BV; ++v) {
      int rowBase = v * 32 + wave * 8;
      int gn = nBase + rowBase + srOff;
      if (gn >= N) gn = N - 1;
      GLOAD_LDS16(B + (size_t)gn * K + k0 + schunk * 8, &Bs[rowBase * BK]);
    }
    __syncthreads();                                   // drains vmcnt (incl. lds-loads)
    #pragma unroll
    for (int kk = 0; kk < BK; kk += 32) {
      const int q = (kk + kHalf) >> 3;                 // global K-chunk wanted
      short8 af[FM], bfv[FN];
      #pragma unroll
      for (int i = 0; i < FM; ++i) {
        int r = wm * WTM + i * 16 + lr;
        af[i] = *(const short8*)(&As[r * BK + ((q ^ (r & 7)) << 3)]);
      }
      #pragma unroll
      for (int j = 0; j < FN; ++j) {
        int r = wn * WTN + j * 16 + lr;
        bfv[j] = *(const short8*)(&Bs[r * BK + ((q ^ (r & 7)) << 3)]);
      }
      #pragma unroll
      for (int i = 0; i < FM; ++i)
        #pragma unroll
        for (int j = 0; j < FN; ++j)
          acc[i][j] = __builtin_amdgcn_mfma_f32_16x16x32_bf16(af[i], bfv[j], acc[i][j], 0, 0, 0);
    }
    __syncthreads();
  }

  // epilogue: D row=(lane>>4)*4+r, col=lane&15 (m89-verified mapping)
  const int rBase = (lane >> 4) << 2;
  #pragma unroll
  for (int i = 0; i < FM; ++i) {
    #pragma unroll
    for (int j = 0; j < FN; ++j) {
      #pragma unroll
      for (int r = 0; r < 4; ++r) {
        int row = mBase + wm * WTM + i * 16 + rBase + r;
        int col = nBase + wn * WTN + j * 16 + lr;
        if (row < M && col < N) {
          float v = acc[i][j][r];
          size_t o = (size_t)row * N + col;
          if (EPI == EP_LOGIT) {
            v = 0.5f * v - 0.25f * aux1[row];
            ((_Float16*)Cout)[o] = (_Float16)v;
          } else if (EPI == EP_TANH) {
            v = tanhf(v + aux1[row]) * aux2[col];
            ((unsigned short*)Cout)[o] = f2bf(v);
          } else if (EPI == EP_BF16) {
            ((unsigned short*)Cout)[o] = f2bf(v);
          } else if (EPI == EP_PART) {
            ((float*)Cout)[(size_t)blockIdx.z * M * N + o] = v;
          } else {
            ((float*)Cout)[o] = v;
          }
        }
      }
    }
  }
}

template<int EPI>
static void launch_gemm(int M, int N, int K, const unsigned short* A, const unsigned short* B,
                        void* C, const float* a1, const float* a2, hipStream_t s) {
  long b128   = (long)cdiv(M, 128) * cdiv(N, 128);
  long b12864 = (long)cdiv(M, 128) * cdiv(N, 64);
  if (b128 >= 192) {
    gemm_nt<128, 128, EPI><<<dim3(cdiv(M, 128), cdiv(N, 128)), 256, 0, s>>>(A, B, C, a1, a2, M, N, K, K);
  } else if (M >= 128 && b12864 >= 192) {
    gemm_nt<128, 64, EPI><<<dim3(cdiv(M, 128), cdiv(N, 64)), 256, 0, s>>>(A, B, C, a1, a2, M, N, K, K);
  } else {
    gemm_nt<64, 64, EPI><<<dim3(cdiv(M, 64), cdiv(N, 64)), 256, 0, s>>>(A, B, C, a1, a2, M, N, K, K);
  }
}

// split-K path for deep-K, small-MN GEMMs; writes fp32 partials then reduces to bf16
static void launch_gemm_splitk(int M, int N, int K, int S,
                               const unsigned short* A, const unsigned short* B,
                               float* Cpart, unsigned short* Cout, hipStream_t s) {
  int kLen = K / S;
  if (M >= 128 && N >= 128) {
    gemm_nt<128, 128, EP_PART><<<dim3(cdiv(M, 128), cdiv(N, 128), S), 256, 0, s>>>(
        A, B, Cpart, nullptr, nullptr, M, N, K, kLen);
  } else {
    gemm_nt<64, 64, EP_PART><<<dim3(cdiv(M, 64), cdiv(N, 64), S), 256, 0, s>>>(
        A, B, Cpart, nullptr, nullptr, M, N, K, kLen);
  }
  int mn = M * N;
  reduce_parts<<<cdiv(mn, 1024), 256, 0, s>>>(Cpart, Cout, mn, S);
}

extern "C" void kernel_launch(void* const* d_in, const int* in_sizes, int n_in,
                              void* d_out, int out_size, void* d_ws, size_t ws_size,
                              hipStream_t stream) {
  const float* h0 = (const float*)d_in[0];
  const float* c1 = (const float*)d_in[1];
  const float* c2 = (const float*)d_in[2];
  const float* c3 = (const float*)d_in[3];
  const float* W1 = (const float*)d_in[4];
  const float* b1 = (const float*)d_in[5];
  const float* W2 = (const float*)d_in[6];
  const float* b2 = (const float*)d_in[7];
  const float* W3 = (const float*)d_in[8];
  const float* b3 = (const float*)d_in[9];

  const int d = 1024;
  const int N0 = 16384, N1 = 2048, N2 = 256, N3 = 32;

  char* w = (char*)d_ws;
  size_t off = 0;
  auto alloc = [&](size_t bytes) {
    void* p = w + off;
    off += (bytes + 255) & ~(size_t)255;
    return p;
  };
  unsigned short* hb  = (unsigned short*)alloc((size_t)N0 * d * 2);   // 32 MB
  unsigned short* cb1 = (unsigned short*)alloc((size_t)N1 * d * 2);
  unsigned short* cb2 = (unsigned short*)alloc((size_t)N2 * d * 2);
  unsigned short* cb3 = (unsigned short*)alloc((size_t)N3 * d * 2);
  float* cn1 = (float*)alloc((size_t)N1 * 4);
  float* cn2 = (float*)alloc((size_t)N2 * 4);
  float* cn3 = (float*)alloc((size_t)N3 * 4);
  unsigned short* Wb1 = (unsigned short*)alloc((size_t)d * d * 2);
  unsigned short* Wb2 = (unsigned short*)alloc((size_t)d * d * 2);
  unsigned short* Wb3 = (unsigned short*)alloc((size_t)d * d * 2);
  _Float16* ST = (_Float16*)alloc((size_t)N1 * N0 * 2);               // 64 MB, E overwrites in place
  unsigned short* tT = (unsigned short*)alloc((size_t)d * N0 * 2);    // 32 MB
  float* linv = (float*)alloc((size_t)N0 * 4);
  float* pmax = (float*)alloc((size_t)32 * N0 * 4);                   // 2 MB partial maxes
  float* psum = (float*)alloc((size_t)32 * N0 * 4);                   // 2 MB partial sums
  unsigned short* h1b = (unsigned short*)alloc((size_t)N1 * d * 2);
  unsigned short* h2b = (unsigned short*)alloc((size_t)N2 * d * 2);
  float* Cpart = (float*)alloc((size_t)8 * N1 * d * 4);               // 64 MB split-K partials
  unsigned short* E = (unsigned short*)ST;
  (void)ws_size; (void)in_sizes; (void)n_in; (void)out_size;

  // ---- prep: bf16 casts + center norms ----
  cast_f32_bf16<<<cdiv(N0 * d, 1024), 256, 0, stream>>>(h0, hb, N0 * d);
  cast_f32_bf16<<<cdiv(d * d, 1024), 256, 0, stream>>>(W1, Wb1, d * d);
  cast_f32_bf16<<<cdiv(d * d, 1024), 256, 0, stream>>>(W2, Wb2, d * d);
  cast_f32_bf16<<<cdiv(d * d, 1024), 256, 0, stream>>>(W3, Wb3, d * d);
  prep_centers<<<N1, 256, 0, stream>>>(c1, cb1, cn1);
  prep_centers<<<N2, 256, 0, stream>>>(c2, cb2, cn2);
  prep_centers<<<N3, 256, 0, stream>>>(c3, cb3, cn3);

  // ---- level 1: h[16384] -> h1[2048] ----
  launch_gemm<EP_LOGIT>(N1, N0, d, cb1, hb, ST, cn1, nullptr, stream);
  softmax_col_launch(ST, pmax, psum, linv, N1, N0, stream);
  launch_gemm<EP_TANH>(d, N0, d, Wb1, hb, tT, b1, linv, stream);
  launch_gemm_splitk(N1, d, N0, 8, E, tT, Cpart, h1b, stream);   // grid 16x8x8 = 1024 blocks

  // ---- level 2: h1[2048] -> h2[256] ----
  launch_gemm<EP_LOGIT>(N2, N1, d, cb2, h1b, ST, cn2, nullptr, stream);
  softmax_col_launch(ST, pmax, psum, linv, N2, N1, stream);
  launch_gemm<EP_TANH>(d, N1, d, Wb2, h1b, tT, b2, linv, stream);
  launch_gemm_splitk(N2, d, N1, 8, E, tT, Cpart, h2b, stream);   // 64x64 tile, 4x16x8 = 512 blocks

  // ---- level 3: h2[256] -> out[32][1024] fp32 ----
  launch_gemm<EP_LOGIT>(N3, N2, d, cb3, h2b, ST, cn3, nullptr, stream);
  softmax_col_launch(ST, pmax, psum, linv, N3, N2, stream);
  launch_gemm<EP_TANH>(d, N2, d, Wb3, h2b, tT, b3, linv, stream);
  launch_gemm<EP_F32>(N3, d, N2, E, tT, d_out, nullptr, nullptr, stream);
}

// Round 5
// 570.151 us; speedup vs baseline: 4.2552x; 1.0109x over previous
//
#include <hip/hip_runtime.h>
#include <cmath>

typedef _Float16 half8 __attribute__((ext_vector_type(8)));
typedef _Float16 half4v __attribute__((ext_vector_type(4)));
typedef __attribute__((ext_vector_type(4))) float floatx4;

#define GLOAD_LDS16(gp, lp)                                            \
  __builtin_amdgcn_global_load_lds(                                    \
      (const __attribute__((address_space(1))) void*)(gp),             \
      (__attribute__((address_space(3))) void*)(lp), 16, 0, 0)

// monotone float<->u32 key for atomicMax-based fp32 max (works for any sign)
__device__ __forceinline__ unsigned fkey(float x) {
  unsigned b = __float_as_uint(x);
  return (b & 0x80000000u) ? ~b : (b | 0x80000000u);
}
__device__ __forceinline__ float fkey_dec(unsigned u) {
  return __uint_as_float((u & 0x80000000u) ? (u & 0x7FFFFFFFu) : ~u);
}

static inline int cdiv(int a, int b) { return (a + b - 1) / b; }

// ---------------- merged prep: cast h0/W1/W2/W3 fp32->fp16 + zero pmaxu ----------------
// layout: [0, nh) -> h ; [nh, nh+nw) -> W1 ; ... ; tail blocks zero pmaxu
__global__ void prep_all(const float* __restrict__ h0, const float* __restrict__ W1,
                         const float* __restrict__ W2, const float* __restrict__ W3,
                         _Float16* __restrict__ hh, _Float16* __restrict__ Wh1,
                         _Float16* __restrict__ Wh2, _Float16* __restrict__ Wh3,
                         unsigned* __restrict__ pmaxu, int nh, int nw, int castBlocks,
                         int nmax) {
  if ((int)blockIdx.x >= castBlocks) {   // pmaxu zeroing tail
    int i = ((int)blockIdx.x - castBlocks) * 1024 + threadIdx.x * 4;
    if (i < nmax) *(uint4*)(pmaxu + i) = make_uint4(0, 0, 0, 0);
    return;
  }
  int gi = (blockIdx.x * 256 + threadIdx.x) * 4;
  const float* src; _Float16* dst; int off;
  if (gi < nh)                { src = h0; dst = hh;  off = gi; }
  else if (gi < nh + nw)      { src = W1; dst = Wh1; off = gi - nh; }
  else if (gi < nh + 2 * nw)  { src = W2; dst = Wh2; off = gi - nh - nw; }
  else if (gi < nh + 3 * nw)  { src = W3; dst = Wh3; off = gi - nh - 2 * nw; }
  else return;
  float4 v = *(const float4*)(src + off);
  half4v o = {(_Float16)v.x, (_Float16)v.y, (_Float16)v.z, (_Float16)v.w};
  *(half4v*)(dst + off) = o;
}

// ------------- centers: cast to fp16 + squared row norms (d=1024), all 3 levels -------------
__global__ void prep_centers(const float* __restrict__ c1, const float* __restrict__ c2,
                             const float* __restrict__ c3, _Float16* __restrict__ cb1,
                             _Float16* __restrict__ cb2, _Float16* __restrict__ cb3,
                             float* __restrict__ cn1, float* __restrict__ cn2,
                             float* __restrict__ cn3, int n1, int n2) {
  int row = blockIdx.x, t = threadIdx.x;  // 256 threads, 4 elems each
  const float* c; _Float16* cb; float* cn;
  if (row < n1)            { c = c1; cb = cb1; cn = cn1; }
  else if (row < n1 + n2)  { row -= n1; c = c2; cb = cb2; cn = cn2; }
  else                     { row -= n1 + n2; c = c3; cb = cb3; cn = cn3; }
  float4 v = *(const float4*)(c + (size_t)row * 1024 + t * 4);
  half4v o = {(_Float16)v.x, (_Float16)v.y, (_Float16)v.z, (_Float16)v.w};
  *(half4v*)(cb + (size_t)row * 1024 + t * 4) = o;
  float s = v.x * v.x + v.y * v.y + v.z * v.z + v.w * v.w;
  #pragma unroll
  for (int off = 32; off > 0; off >>= 1) s += __shfl_down(s, off, 64);
  __shared__ float ws[4];
  if ((t & 63) == 0) ws[t >> 6] = s;
  __syncthreads();
  if (t == 0) cn[row] = ws[0] + ws[1] + ws[2] + ws[3];
}

// ------------- parallel column softmax over ST[ncur][nprev] (fp16), max from pmaxu -------------
#define SM_CHUNK 64
// exp in place (fp16 E), partial sums per 64-row chunk; 4 cols/thread
__global__ void colexp_partial(_Float16* __restrict__ ST, const unsigned* __restrict__ pmaxu,
                               float* __restrict__ psum, int ncur, int nprev) {
  int col = (blockIdx.x * 256 + threadIdx.x) * 4;
  if (col >= nprev) return;
  uint4 mk = *(const uint4*)(pmaxu + col);
  float m0 = fkey_dec(mk.x), m1 = fkey_dec(mk.y), m2 = fkey_dec(mk.z), m3 = fkey_dec(mk.w);
  int j0 = blockIdx.y * SM_CHUNK;
  int j1 = min(j0 + SM_CHUNK, ncur);
  float s0 = 0.f, s1 = 0.f, s2 = 0.f, s3 = 0.f;
  for (int j = j0; j < j1; ++j) {
    size_t o = (size_t)j * nprev + col;
    half4v x = *(const half4v*)(ST + o);
    float e0 = __expf((float)x[0] - m0), e1 = __expf((float)x[1] - m1);
    float e2 = __expf((float)x[2] - m2), e3 = __expf((float)x[3] - m3);
    half4v e = {(_Float16)e0, (_Float16)e1, (_Float16)e2, (_Float16)e3};
    *(half4v*)(ST + o) = e;
    s0 += e0; s1 += e1; s2 += e2; s3 += e3;
  }
  float4 sv = {s0, s1, s2, s3};
  *(float4*)(psum + (size_t)blockIdx.y * nprev + col) = sv;
}

// linv = 1/sum; also re-zero pmaxu for the next level (nprev shrinks monotonically)
__global__ void colfin(const float* __restrict__ psum, float* __restrict__ linv,
                       unsigned* __restrict__ pmaxu, int nchunks, int nprev) {
  int col = (blockIdx.x * 256 + threadIdx.x) * 4;
  if (col >= nprev) return;
  float4 a = *(const float4*)(psum + col);
  for (int k = 1; k < nchunks; ++k) {
    float4 v = *(const float4*)(psum + (size_t)k * nprev + col);
    a.x += v.x; a.y += v.y; a.z += v.z; a.w += v.w;
  }
  float4 r = {1.f / a.x, 1.f / a.y, 1.f / a.z, 1.f / a.w};
  *(float4*)(linv + col) = r;
  *(uint4*)(pmaxu + col) = make_uint4(0, 0, 0, 0);
}

// ---------------- split-K reduce: out_fp16[i] = sum_s part[s][i] ----------------
__global__ void reduce_parts(const float* __restrict__ part, _Float16* __restrict__ out,
                             int mn, int S) {
  int i = (blockIdx.x * 256 + threadIdx.x) * 4;
  if (i >= mn) return;
  float4 a = *(const float4*)(part + i);
  for (int s = 1; s < S; ++s) {
    float4 v = *(const float4*)(part + (size_t)s * mn + i);
    a.x += v.x; a.y += v.y; a.z += v.z; a.w += v.w;
  }
  half4v o = {(_Float16)a.x, (_Float16)a.y, (_Float16)a.z, (_Float16)a.w};
  *(half4v*)(out + i) = o;
}

// ---------------- NT fp16 MFMA GEMM: C[M][N] = A[M][K] * B[N][K]^T ----------------
// global_load_lds (16B) staging, XOR-swizzled LDS (conflict-free, see r3/r4 notes).
// EP_LOGIT additionally feeds a per-column running max via atomicMax on keyed u32.
enum { EP_LOGIT = 0, EP_TANH = 1, EP_F16 = 2, EP_F32 = 3, EP_PART = 4 };

template<int BM, int BN, int EPI>
__launch_bounds__(256, 4)
__global__ void gemm_nt(const _Float16* __restrict__ A,
                        const _Float16* __restrict__ B,
                        void* __restrict__ Cout,
                        const float* __restrict__ aux1,   // cn[M] or bias[M]
                        const float* __restrict__ aux2,   // linv[N]
                        unsigned* __restrict__ pmaxu,     // EP_LOGIT only
                        int M, int N, int K, int kLen) {
  constexpr int BK = 64;                 // 128 B/row, unpadded (global_load_lds needs it)
  constexpr int WTM = BM / 2, WTN = BN / 2;
  constexpr int FM = WTM / 16, FN = WTN / 16;
  __shared__ __align__(16) _Float16 As[BM * BK];
  __shared__ __align__(16) _Float16 Bs[BN * BK];
  const int tid  = threadIdx.x;
  const int lane = tid & 63;
  const int wave = tid >> 6;
  const int wm = wave >> 1, wn = wave & 1;
  const int mBase = blockIdx.x * BM, nBase = blockIdx.y * BN;
  const int kBase = blockIdx.z * kLen;
  const int lr    = lane & 15;           // fragment row (A: m, B: n)
  const int kHalf = (lane >> 4) << 3;    // fragment k offset: 0,8,16,24

  const int srOff  = lane >> 3;                        // row within 8-row staging group
  const int schunk = (lane & 7) ^ srOff;               // swizzled global K-chunk
  floatx4 acc[FM][FN] = {};
  constexpr int AV = BM * BK / (256 * 8);
  constexpr int BV = BN * BK / (256 * 8);

  for (int k0 = kBase; k0 < kBase + kLen; k0 += BK) {  // kLen % 64 == 0 everywhere
    #pragma unroll
    for (int v = 0; v < AV; ++v) {
      int rowBase = v * 32 + wave * 8;
      int gm = mBase + rowBase + srOff;
      if (gm >= M) gm = M - 1;                         // clamp: feeds only discarded rows
      GLOAD_LDS16(A + (size_t)gm * K + k0 + schunk * 8, &As[rowBase * BK]);
    }
    #pragma unroll
    for (int v = 0; v < BV; ++v) {
      int rowBase = v * 32 + wave * 8;
      int gn = nBase + rowBase + srOff;
      if (gn >= N) gn = N - 1;
      GLOAD_LDS16(B + (size_t)gn * K + k0 + schunk * 8, &Bs[rowBase * BK]);
    }
    __syncthreads();
    #pragma unroll
    for (int kk = 0; kk < BK; kk += 32) {
      const int q = (kk + kHalf) >> 3;
      half8 af[FM], bfv[FN];
      #pragma unroll
      for (int i = 0; i < FM; ++i) {
        int r = wm * WTM + i * 16 + lr;
        af[i] = *(const half8*)(&As[r * BK + ((q ^ (r & 7)) << 3)]);
      }
      #pragma unroll
      for (int j = 0; j < FN; ++j) {
        int r = wn * WTN + j * 16 + lr;
        bfv[j] = *(const half8*)(&Bs[r * BK + ((q ^ (r & 7)) << 3)]);
      }
      #pragma unroll
      for (int i = 0; i < FM; ++i)
        #pragma unroll
        for (int j = 0; j < FN; ++j)
          acc[i][j] = __builtin_amdgcn_mfma_f32_16x16x32_f16(af[i], bfv[j], acc[i][j], 0, 0, 0);
    }
    __syncthreads();
  }

  // epilogue: D row=(lane>>4)*4+r, col=lane&15 (m89-verified mapping)
  const int rBase = (lane >> 4) << 2;
  float lmax[FN];
  #pragma unroll
  for (int j = 0; j < FN; ++j) lmax[j] = -1e30f;
  #pragma unroll
  for (int i = 0; i < FM; ++i) {
    #pragma unroll
    for (int j = 0; j < FN; ++j) {
      #pragma unroll
      for (int r = 0; r < 4; ++r) {
        int row = mBase + wm * WTM + i * 16 + rBase + r;
        int col = nBase + wn * WTN + j * 16 + lr;
        if (row < M && col < N) {
          float v = acc[i][j][r];
          size_t o = (size_t)row * N + col;
          if (EPI == EP_LOGIT) {
            v = 0.5f * v - 0.25f * aux1[row];
            ((_Float16*)Cout)[o] = (_Float16)v;
            lmax[j] = fmaxf(lmax[j], v);
          } else if (EPI == EP_TANH) {
            v = tanhf(v + aux1[row]) * aux2[col];
            ((_Float16*)Cout)[o] = (_Float16)v;
          } else if (EPI == EP_F16) {
            ((_Float16*)Cout)[o] = (_Float16)v;
          } else if (EPI == EP_PART) {
            ((float*)Cout)[(size_t)blockIdx.z * M * N + o] = v;
          } else {
            ((float*)Cout)[o] = v;
          }
        }
      }
    }
  }
  if (EPI == EP_LOGIT) {
    #pragma unroll
    for (int j = 0; j < FN; ++j) {
      int col = nBase + wn * WTN + j * 16 + lr;
      if (col < N && lmax[j] > -1e29f)
        atomicMax(pmaxu + col, fkey(lmax[j]));
    }
  }
}

template<int EPI>
static void launch_gemm(int M, int N, int K, const _Float16* A, const _Float16* B,
                        void* C, const float* a1, const float* a2, unsigned* pmaxu,
                        hipStream_t s) {
  long b128   = (long)cdiv(M, 128) * cdiv(N, 128);
  long b12864 = (long)cdiv(M, 128) * cdiv(N, 64);
  if (b128 >= 192) {
    gemm_nt<128, 128, EPI><<<dim3(cdiv(M, 128), cdiv(N, 128)), 256, 0, s>>>(A, B, C, a1, a2, pmaxu, M, N, K, K);
  } else if (M >= 128 && b12864 >= 192) {
    gemm_nt<128, 64, EPI><<<dim3(cdiv(M, 128), cdiv(N, 64)), 256, 0, s>>>(A, B, C, a1, a2, pmaxu, M, N, K, K);
  } else {
    gemm_nt<64, 64, EPI><<<dim3(cdiv(M, 64), cdiv(N, 64)), 256, 0, s>>>(A, B, C, a1, a2, pmaxu, M, N, K, K);
  }
}

static void launch_gemm_splitk(int M, int N, int K, int S,
                               const _Float16* A, const _Float16* B,
                               float* Cpart, _Float16* Cout, hipStream_t s) {
  int kLen = K / S;
  if (M >= 128 && N >= 128) {
    gemm_nt<128, 128, EP_PART><<<dim3(cdiv(M, 128), cdiv(N, 128), S), 256, 0, s>>>(
        A, B, Cpart, nullptr, nullptr, nullptr, M, N, K, kLen);
  } else {
    gemm_nt<64, 64, EP_PART><<<dim3(cdiv(M, 64), cdiv(N, 64), S), 256, 0, s>>>(
        A, B, Cpart, nullptr, nullptr, nullptr, M, N, K, kLen);
  }
  int mn = M * N;
  reduce_parts<<<cdiv(mn, 1024), 256, 0, s>>>(Cpart, Cout, mn, S);
}

static void softmax_launch(_Float16* ST, unsigned* pmaxu, float* psum, float* linv,
                           int ncur, int nprev, hipStream_t s) {
  int nchunks = cdiv(ncur, SM_CHUNK);
  dim3 g(cdiv(nprev, 1024), nchunks);
  colexp_partial<<<g, 256, 0, s>>>(ST, pmaxu, psum, ncur, nprev);
  colfin<<<cdiv(nprev, 1024), 256, 0, s>>>(psum, linv, pmaxu, nchunks, nprev);
}

extern "C" void kernel_launch(void* const* d_in, const int* in_sizes, int n_in,
                              void* d_out, int out_size, void* d_ws, size_t ws_size,
                              hipStream_t stream) {
  const float* h0 = (const float*)d_in[0];
  const float* c1 = (const float*)d_in[1];
  const float* c2 = (const float*)d_in[2];
  const float* c3 = (const float*)d_in[3];
  const float* W1 = (const float*)d_in[4];
  const float* b1 = (const float*)d_in[5];
  const float* W2 = (const float*)d_in[6];
  const float* b2 = (const float*)d_in[7];
  const float* W3 = (const float*)d_in[8];
  const float* b3 = (const float*)d_in[9];

  const int d = 1024;
  const int N0 = 16384, N1 = 2048, N2 = 256, N3 = 32;

  char* w = (char*)d_ws;
  size_t off = 0;
  auto alloc = [&](size_t bytes) {
    void* p = w + off;
    off += (bytes + 255) & ~(size_t)255;
    return p;
  };
  _Float16* hb  = (_Float16*)alloc((size_t)N0 * d * 2);   // 32 MB
  _Float16* cb1 = (_Float16*)alloc((size_t)N1 * d * 2);
  _Float16* cb2 = (_Float16*)alloc((size_t)N2 * d * 2);
  _Float16* cb3 = (_Float16*)alloc((size_t)N3 * d * 2);
  float* cn1 = (float*)alloc((size_t)N1 * 4);
  float* cn2 = (float*)alloc((size_t)N2 * 4);
  float* cn3 = (float*)alloc((size_t)N3 * 4);
  _Float16* Wb1 = (_Float16*)alloc((size_t)d * d * 2);
  _Float16* Wb2 = (_Float16*)alloc((size_t)d * d * 2);
  _Float16* Wb3 = (_Float16*)alloc((size_t)d * d * 2);
  _Float16* ST = (_Float16*)alloc((size_t)N1 * N0 * 2);   // 64 MB, E overwrites in place
  _Float16* tT = (_Float16*)alloc((size_t)d * N0 * 2);    // 32 MB
  float* linv = (float*)alloc((size_t)N0 * 4);
  unsigned* pmaxu = (unsigned*)alloc((size_t)N0 * 4);     // keyed column maxes
  float* psum = (float*)alloc((size_t)32 * N0 * 4);       // 2 MB partial sums
  _Float16* h1b = (_Float16*)alloc((size_t)N1 * d * 2);
  _Float16* h2b = (_Float16*)alloc((size_t)N2 * d * 2);
  float* Cpart = (float*)alloc((size_t)8 * N1 * d * 4);   // 64 MB split-K partials
  _Float16* E = ST;
  (void)ws_size; (void)in_sizes; (void)n_in; (void)out_size;

  // ---- prep: fp16 casts + center norms + pmaxu zero (2 launches) ----
  int nh = N0 * d, nw = d * d;
  int castBlocks = cdiv(nh + 3 * nw, 1024);
  int zeroBlocks = cdiv(N0, 1024);
  prep_all<<<castBlocks + zeroBlocks, 256, 0, stream>>>(
      h0, W1, W2, W3, hb, Wb1, Wb2, Wb3, pmaxu, nh, nw, castBlocks, N0);
  prep_centers<<<N1 + N2 + N3, 256, 0, stream>>>(c1, c2, c3, cb1, cb2, cb3,
                                                 cn1, cn2, cn3, N1, N2);

  // ---- level 1: h[16384] -> h1[2048] ----
  launch_gemm<EP_LOGIT>(N1, N0, d, cb1, hb, ST, cn1, nullptr, pmaxu, stream);
  softmax_launch(ST, pmaxu, psum, linv, N1, N0, stream);
  launch_gemm<EP_TANH>(d, N0, d, Wb1, hb, tT, b1, linv, nullptr, stream);
  launch_gemm_splitk(N1, d, N0, 8, E, tT, Cpart, h1b, stream);   // 16x8x8 = 1024 blocks

  // ---- level 2: h1[2048] -> h2[256] ----
  launch_gemm<EP_LOGIT>(N2, N1, d, cb2, h1b, ST, cn2, nullptr, pmaxu, stream);
  softmax_launch(ST, pmaxu, psum, linv, N2, N1, stream);
  launch_gemm<EP_TANH>(d, N1, d, Wb2, h1b, tT, b2, linv, nullptr, stream);
  launch_gemm_splitk(N2, d, N1, 8, E, tT, Cpart, h2b, stream);   // 2x8x8 = 128 blocks

  // ---- level 3: h2[256] -> out[32][1024] fp32 ----
  launch_gemm<EP_LOGIT>(N3, N2, d, cb3, h2b, ST, cn3, nullptr, pmaxu, stream);
  softmax_launch(ST, pmaxu, psum, linv, N3, N2, stream);
  launch_gemm<EP_TANH>(d, N2, d, Wb3, h2b, tT, b3, linv, nullptr, stream);
  launch_gemm<EP_F32>(N3, d, N2, E, tT, d_out, nullptr, nullptr, nullptr, stream);
}